// Round 2
// 259.846 us; speedup vs baseline: 1.0370x; 1.0370x over previous
//
#include <hip/hip_runtime.h>
#include <math.h>

#define N_NODES 50000
#define N_EDGES 500000
#define HIDDEN 128
#define HEADS 8
#define HEAD_DIM 16

#define QB 391                   // ceil(50000/128) q-blocks
#define QKV_TOTAL 782            // q-blocks + kv-blocks
#define SCAT_BLOCKS 1954         // ceil(500000/256)
#define SPLITW_BLOCKS 320        // 5*16384/256
#define ZERO_BLOCKS 196          // ceil(50000/256)

typedef __attribute__((ext_vector_type(8))) short short8;     // 8 bf16 (4 VGPRs) MFMA A/B frag
typedef __attribute__((ext_vector_type(4))) float floatx4;    // MFMA C/D frag

// workspace layout, element offsets (4-byte units)
#define OFF_Q       0u           // scan scratch (pre-qkv) -> q fp32 [50000x128]
#define OFF_KV      6400000u     // kv packed bf16 pairs [50000x128] (k lo16, v hi16)
#define OFF_HHI     12800000u    // rank [500000 ints] (pre-edge) -> hupd_hi bf16 [50000x128]
#define OFF_HLO     16000000u    // hupd_lo bf16 [50000x128]
#define OFF_DISP    19200000u    // 150,000 floats
#define OFF_CNT     19350016u    // 50,000 ints
#define OFF_ROWPTR  19400032u    // 50,001 ints
#define OFF_CURSOR  19450048u    // (unused now)
#define OFF_ESD     19500064u    // 1,000,000 ints (int2 per edge: dst, dist^2 bits, CSR order)
#define OFF_WSPLIT  20500064u    // W{q,k,v,o,g1} split-bf16 frag order: 81,920 float slots

static __device__ __forceinline__ unsigned short f2bf(float f) {
    unsigned u = __builtin_bit_cast(unsigned, f);
    unsigned r = (u + 0x7FFFu + ((u >> 16) & 1u)) >> 16;      // RNE
    return (unsigned short)r;
}
static __device__ __forceinline__ float bf2f(unsigned short s) {
    return __builtin_bit_cast(float, (unsigned)s << 16);
}

// prep: blocks [0,320) repack W{q,k,v,o,g1} into split-bf16 MFMA B-frag order;
// blocks [320,516) zero the degree counters. (identical to measured baseline)
__global__ void k_prep(const float* __restrict__ Wq, const float* __restrict__ Wk,
                       const float* __restrict__ Wv, const float* __restrict__ Wo,
                       const float* __restrict__ Wg1, unsigned short* __restrict__ ws,
                       int* __restrict__ cnt) {
    if (blockIdx.x >= SPLITW_BLOCKS) {
        int i = (int)(blockIdx.x - SPLITW_BLOCKS) * 256 + threadIdx.x;
        if (i < N_NODES) cnt[i] = 0;
        return;
    }
    int t = blockIdx.x * 256 + threadIdx.x;          // exact: 5*16384
    int m = t >> 14, r = t & 16383;
    int k = r >> 7, n = r & 127;
    const float* W = (m == 0) ? Wq : (m == 1) ? Wk : (m == 2) ? Wv : (m == 3) ? Wo : Wg1;
    float x = W[k * 128 + n];
    int kc = k >> 5, kin = k & 31, quad = kin >> 3, j = kin & 7;
    int ct = n >> 4, nin = n & 15, lane = quad * 16 + nin;
    unsigned base = ((((unsigned)(m * 4 + kc) * 8 + ct) * 2) * 64 + lane) * 8 + j;
    unsigned short a = f2bf(x);
    ws[base] = a;                                    // hilo=0
    ws[base + 512] = f2bf(x - bf2f(a));              // hilo=1 (+64 lanes*8)
}

// degree histogram + per-edge rank (arrival order within segment).
// rank makes the CSR scatter in k_qkv_scatter atomic-free.
__global__ void k_count(const int* __restrict__ src, int* __restrict__ cnt,
                        int* __restrict__ rnk) {
    int e = blockIdx.x * 256 + threadIdx.x;
    if (e < N_EDGES) rnk[e] = atomicAdd(&cnt[src[e]], 1);
}

// hierarchical scan over 50000 counts: per-block inclusive scan + block sums
__global__ __launch_bounds__(1024) void k_scan1(const int* __restrict__ cnt,
                                                int* __restrict__ loc,
                                                int* __restrict__ bsum, int n) {
    __shared__ int buf[1024];
    int t = threadIdx.x;
    int i = blockIdx.x * 1024 + t;
    int val = (i < n) ? cnt[i] : 0;
    buf[t] = val;
    __syncthreads();
    for (int off = 1; off < 1024; off <<= 1) {
        int a = (t >= off) ? buf[t - off] : 0;
        __syncthreads();
        buf[t] += a;
        __syncthreads();
    }
    if (i < n) loc[i] = buf[t];
    if (t == 1023) bsum[blockIdx.x] = buf[1023];
}

// scan2+scan3 fused: wave-scan the <=64 block sums, emit rowptr.
__global__ __launch_bounds__(256) void k_scan23(const int* __restrict__ loc,
                                                const int* __restrict__ bsum,
                                                int* __restrict__ rowptr, int n, int nb) {
    __shared__ int sb[64];
    int t = threadIdx.x;
    if (t < 64) {
        int v = (t < nb) ? bsum[t] : 0;
        for (int off = 1; off < 64; off <<= 1) {
            int a = __shfl_up(v, off);
            if (t >= off) v += a;
        }
        sb[t] = v;                                   // inclusive scan of block sums
    }
    __syncthreads();
    int i = blockIdx.x * 256 + t;
    if (i < n) {
        int off = (i >= 1024) ? sb[(i >> 10) - 1] : 0;
        rowptr[i + 1] = loc[i] + off;
    }
    if (i == 0) rowptr[0] = 0;
}

// FUSED qkv + scatter, v2:
//  blocks [0,391):       q = h@Wq   (128 rows/block, Wq staged once in 64KB LDS)
//  blocks [391,782):     k,v = h@Wk, h@Wv two-phase (Wk then Wv staged in same LDS;
//                        A-frags of h held in VGPRs across phases; k packed in regs)
//  blocks [782,2736):    atomic-free CSR scatter: pos = rowptr[src] + rank[e]
// Weight L2 traffic drops 300MB -> 73MB; B-frag reads become pipelined ds_read_b128.
__global__ __launch_bounds__(256, 2) void k_qkv_scatter(
    const float* __restrict__ h, const unsigned short* __restrict__ wsp,
    const float* __restrict__ bq, const float* __restrict__ bk, const float* __restrict__ bv,
    float* __restrict__ q, unsigned* __restrict__ kvp,
    const int* __restrict__ src, const int* __restrict__ dst,
    const float* __restrict__ dist, const int* __restrict__ rowptr,
    const int* __restrict__ rnk, int2* __restrict__ esd) {
    if (blockIdx.x >= QKV_TOTAL) {
        int e = (int)(blockIdx.x - QKV_TOTAL) * 256 + threadIdx.x;
        if (e < N_EDGES) {
            int s = src[e];
            float dd = dist[e];
            int pos = rowptr[s] + rnk[e];
            esd[pos] = make_int2(dst[e], __float_as_int(dd * dd));
        }
        return;
    }

    __shared__ short lds[32768];                     // 64 KB: one mat in frag order
    const int tid = threadIdx.x;
    const int wave = tid >> 6, lane = tid & 63;
    const int quad = lane >> 4, l15 = lane & 15;
    const bool iskv = (blockIdx.x >= QB);
    const int blk = iskv ? (int)blockIdx.x - QB : (int)blockIdx.x;
    const int row0 = blk * 128 + wave * 32;          // this wave's 32 rows

    // A fragments: 32 rows of h, hi/lo bf16 split, held in VGPRs for all phases
    short8 ah[2][4], al[2][4];                       // [rt][kc]
#pragma unroll
    for (int rt = 0; rt < 2; ++rt) {
        int row = row0 + rt * 16 + l15;
        if (row >= N_NODES) row = N_NODES - 1;
        const float* hp = h + (size_t)row * 128;
#pragma unroll
        for (int kc = 0; kc < 4; ++kc) {
            const float* p = hp + kc * 32 + quad * 8;
            float4 f0 = *(const float4*)(p);
            float4 f1 = *(const float4*)(p + 4);
            float fv[8] = {f0.x, f0.y, f0.z, f0.w, f1.x, f1.y, f1.z, f1.w};
#pragma unroll
            for (int j = 0; j < 8; ++j) {
                unsigned short hi = f2bf(fv[j]);
                ah[rt][kc][j] = (short)hi;
                al[rt][kc][j] = (short)f2bf(fv[j] - bf2f(hi));
            }
        }
    }

    auto stage = [&](int m) {                        // copy mat m (64 KB) to LDS
        const float4* s4 = (const float4*)(wsp + (unsigned)m * 32768u);
        float4* d4 = (float4*)lds;
#pragma unroll 4
        for (int it = tid; it < 4096; it += 256) d4[it] = s4[it];
    };

    auto compute = [&](floatx4 (&acc)[2][8]) {       // full 128-K MFMA over staged mat
#pragma unroll
        for (int kc = 0; kc < 4; ++kc) {
#pragma unroll
            for (int ct = 0; ct < 8; ++ct) {
                const short* tb = lds + (((kc * 8 + ct) * 2) * 64 + lane) * 8;
                short8 bh = *(const short8*)(tb);
                short8 bl = *(const short8*)(tb + 512);
#pragma unroll
                for (int rt = 0; rt < 2; ++rt) {
                    acc[rt][ct] = __builtin_amdgcn_mfma_f32_16x16x32_bf16(
                        ah[rt][kc], bh, acc[rt][ct], 0, 0, 0);
                    acc[rt][ct] = __builtin_amdgcn_mfma_f32_16x16x32_bf16(
                        ah[rt][kc], bl, acc[rt][ct], 0, 0, 0);
                    acc[rt][ct] = __builtin_amdgcn_mfma_f32_16x16x32_bf16(
                        al[rt][kc], bh, acc[rt][ct], 0, 0, 0);
                }
            }
        }
    };

    if (!iskv) {
        stage(0);
        __syncthreads();
        floatx4 acc[2][8];
#pragma unroll
        for (int rt = 0; rt < 2; ++rt)
#pragma unroll
            for (int ct = 0; ct < 8; ++ct) acc[rt][ct] = (floatx4){0.f, 0.f, 0.f, 0.f};
        compute(acc);
#pragma unroll
        for (int ct = 0; ct < 8; ++ct) {
            int col = ct * 16 + l15;
            float b = bq[col];
#pragma unroll
            for (int rt = 0; rt < 2; ++rt)
#pragma unroll
                for (int reg = 0; reg < 4; ++reg) {
                    int row = row0 + rt * 16 + quad * 4 + reg;
                    if (row < N_NODES) q[(size_t)row * 128 + col] = acc[rt][ct][reg] + b;
                }
        }
    } else {
        // ---- phase K ----
        stage(1);
        __syncthreads();
        floatx4 acc[2][8];
#pragma unroll
        for (int rt = 0; rt < 2; ++rt)
#pragma unroll
            for (int ct = 0; ct < 8; ++ct) acc[rt][ct] = (floatx4){0.f, 0.f, 0.f, 0.f};
        compute(acc);
        unsigned kb[2][8][2];                        // packed bf16 k, 2 regs/dword
#pragma unroll
        for (int ct = 0; ct < 8; ++ct) {
            float b = bk[ct * 16 + l15];
#pragma unroll
            for (int rt = 0; rt < 2; ++rt) {
                kb[rt][ct][0] = (unsigned)f2bf(acc[rt][ct][0] + b) |
                                ((unsigned)f2bf(acc[rt][ct][1] + b) << 16);
                kb[rt][ct][1] = (unsigned)f2bf(acc[rt][ct][2] + b) |
                                ((unsigned)f2bf(acc[rt][ct][3] + b) << 16);
            }
        }
        __syncthreads();                             // all waves done reading Wk
        // ---- phase V ----
        stage(2);
        __syncthreads();
#pragma unroll
        for (int rt = 0; rt < 2; ++rt)
#pragma unroll
            for (int ct = 0; ct < 8; ++ct) acc[rt][ct] = (floatx4){0.f, 0.f, 0.f, 0.f};
        compute(acc);
#pragma unroll
        for (int ct = 0; ct < 8; ++ct) {
            int col = ct * 16 + l15;
            float b = bv[col];
#pragma unroll
            for (int rt = 0; rt < 2; ++rt)
#pragma unroll
                for (int reg = 0; reg < 4; ++reg) {
                    int row = row0 + rt * 16 + quad * 4 + reg;
                    unsigned vb = f2bf(acc[rt][ct][reg] + b);
                    unsigned kw = (kb[rt][ct][reg >> 1] >> ((reg & 1) * 16)) & 0xFFFFu;
                    if (row < N_NODES) kvp[(size_t)row * 128 + col] = kw | (vb << 16);
                }
        }
    }
}

// FUSED edge+node: one wave per node, 4-edge batched inner loop (proven
// config: VGPR 32, ~63% occupancy, ~3.3 TB/s).
__global__ __launch_bounds__(256) void k_edge_node(
    const float* __restrict__ q, const unsigned* __restrict__ kvp,
    const float* __restrict__ x,
    const int2* __restrict__ esd, const int* __restrict__ rowptr,
    const float* __restrict__ Wd, const float* __restrict__ bd,
    unsigned short* __restrict__ hupd_hi, unsigned short* __restrict__ hupd_lo,
    float* __restrict__ disp) {
    const int wave = threadIdx.x >> 6, lane = threadIdx.x & 63;
    const int node = blockIdx.x * 4 + wave;           // grid exact: N/4 blocks
    const int h = lane >> 3, sub = lane & 7;          // head, within-head slot
    const int beg = rowptr[node], end = rowptr[node + 1];

    const float2 qv = *(const float2*)(q + (size_t)node * 128 + 2 * lane);
    const float wdh = Wd[h], bdh = bd[h];
    const bool dal = (sub < 3);
    float xs = dal ? x[node * 3 + sub] : 0.f;
    const unsigned colo = 2 * lane;

    float acc0 = 0.f, acc1 = 0.f, s_own = 0.f, da = 0.f;

    for (int cb = beg; cb < end; cb += 64) {
        int idx = cb + lane;
        int dvec = 0; float d2vec = 0.f;
        if (idx < end) {
            int2 ed = esd[idx];
            dvec = ed.x;
            d2vec = __int_as_float(ed.y);
        }
        int clen = min(64, end - cb);
        int i = 0;
        for (; i + 4 <= clen; i += 4) {
            int di[4]; float dd2[4]; uint2 kv2[4]; float xg[4];
#pragma unroll
            for (int j = 0; j < 4; ++j) {
                di[j]  = __shfl(dvec, i + j);
                dd2[j] = __shfl(d2vec, i + j);
            }
#pragma unroll
            for (int j = 0; j < 4; ++j)
                kv2[j] = *(const uint2*)(kvp + (unsigned)di[j] * 128u + colo);
#pragma unroll
            for (int j = 0; j < 4; ++j)
                xg[j] = dal ? x[(unsigned)di[j] * 3u + sub] : 0.f;
#pragma unroll
            for (int j = 0; j < 4; ++j) {
                float k0 = __builtin_bit_cast(float, kv2[j].x << 16);
                float v0 = __builtin_bit_cast(float, kv2[j].x & 0xFFFF0000u);
                float k1 = __builtin_bit_cast(float, kv2[j].y << 16);
                float v1 = __builtin_bit_cast(float, kv2[j].y & 0xFFFF0000u);
                float p = qv.x * k0 + qv.y * k1;
                p += __shfl_xor(p, 1);
                p += __shfl_xor(p, 2);
                p += __shfl_xor(p, 4);                 // all 8 lanes of head h: full dot
                float w = __expf(p * 0.25f - (dd2[j] * wdh + bdh));
                s_own += w;
                acc0 += v0 * w;
                acc1 += v1 * w;
                da += (xg[j] - xs) * w;                // xs=xg=0 on non-da lanes
            }
        }
        for (; i < clen; ++i) {
            int dij  = __shfl(dvec, i);
            float d2 = __shfl(d2vec, i);
            uint2 kv2 = *(const uint2*)(kvp + (unsigned)dij * 128u + colo);
            float xgj = dal ? x[(unsigned)dij * 3u + sub] : 0.f;
            float k0 = __builtin_bit_cast(float, kv2.x << 16);
            float v0 = __builtin_bit_cast(float, kv2.x & 0xFFFF0000u);
            float k1 = __builtin_bit_cast(float, kv2.y << 16);
            float v1 = __builtin_bit_cast(float, kv2.y & 0xFFFF0000u);
            float p = qv.x * k0 + qv.y * k1;
            p += __shfl_xor(p, 1);
            p += __shfl_xor(p, 2);
            p += __shfl_xor(p, 4);
            float w = __expf(p * 0.25f - (d2 * wdh + bdh));
            s_own += w;
            acc0 += v0 * w;
            acc1 += v1 * w;
            da += (xgj - xs) * w;
        }
    }

    float inva = 1.f / fmaxf(s_own, 1e-9f);
    float o0 = acc0 * inva, o1 = acc1 * inva;
    unsigned short h0 = f2bf(o0), h1 = f2bf(o1);
    unsigned short l0 = f2bf(o0 - bf2f(h0)), l1 = f2bf(o1 - bf2f(h1));
    ((unsigned*)hupd_hi)[(size_t)node * 64 + lane] = (unsigned)h0 | ((unsigned)h1 << 16);
    ((unsigned*)hupd_lo)[(size_t)node * 64 + lane] = (unsigned)l0 | ((unsigned)l1 << 16);

    da *= 0.125f * inva;
    da += __shfl_xor(da, 8);
    da += __shfl_xor(da, 16);
    da += __shfl_xor(da, 32);
    if (lane < 3) disp[node * 3 + lane] = da;
}

// fused MFMA epilogue (proven geometry: block=256, 16 rows/wave):
// hout = h + hupd@Wo + bo (GEMM1); hout staged in per-wave padded LDS;
// GEMM2 = hout@Wg1; gate = tanh(sum silu(.)*Wg2); xout = x + gate*disp.
__global__ __launch_bounds__(256) void k_hout_gate(
    const float* __restrict__ h,
    const unsigned short* __restrict__ hupd_hi, const unsigned short* __restrict__ hupd_lo,
    const unsigned short* __restrict__ wsp,
    const float* __restrict__ bo, const float* __restrict__ bg1,
    const float* __restrict__ Wg2, const float* __restrict__ bg2,
    const float* __restrict__ x, const float* __restrict__ disp,
    float* __restrict__ hout, float* __restrict__ xout) {
    __shared__ float hb[4][16 * 132];                 // +4 dword pad per row
    const int wave = threadIdx.x >> 6, lane = threadIdx.x & 63;
    const int quad = lane >> 4, l15 = lane & 15;
    const int row0 = blockIdx.x * 64 + wave * 16;
    float* hbw = hb[wave];

    // ---- GEMM1: hupd @ Wo (m=3) ----
    floatx4 acc[8];
#pragma unroll
    for (int c = 0; c < 8; ++c) acc[c] = (floatx4){0.f, 0.f, 0.f, 0.f};
#pragma unroll
    for (int kc = 0; kc < 4; ++kc) {
        int row = row0 + l15;
        if (row >= N_NODES) row = N_NODES - 1;
        size_t aoff = (size_t)row * 128 + kc * 32 + quad * 8;
        short8 ah = *(const short8*)(hupd_hi + aoff);
        short8 al = *(const short8*)(hupd_lo + aoff);
#pragma unroll
        for (int ct = 0; ct < 8; ++ct) {
            unsigned fb = ((((unsigned)(3 * 4 + kc) * 8 + ct) * 2) * 64 + lane) * 8;
            short8 bh = *(const short8*)(wsp + fb);
            short8 bl = *(const short8*)(wsp + fb + 512);
            acc[ct] = __builtin_amdgcn_mfma_f32_16x16x32_bf16(ah, bh, acc[ct], 0, 0, 0);
            acc[ct] = __builtin_amdgcn_mfma_f32_16x16x32_bf16(ah, bl, acc[ct], 0, 0, 0);
            acc[ct] = __builtin_amdgcn_mfma_f32_16x16x32_bf16(al, bh, acc[ct], 0, 0, 0);
        }
    }

    // epilogue 1: add h + bo, write hout (global) + LDS tile
#pragma unroll
    for (int ct = 0; ct < 8; ++ct) {
        int col = ct * 16 + l15;
        float bias = bo[col];
#pragma unroll
        for (int reg = 0; reg < 4; ++reg) {
            int row = row0 + quad * 4 + reg;
            float val = acc[ct][reg] + bias;
            if (row < N_NODES) {
                val += h[(size_t)row * 128 + col];
                hout[(size_t)row * 128 + col] = val;
            }
            hbw[(quad * 4 + reg) * 132 + col] = val;
        }
    }
    __asm__ volatile("s_waitcnt lgkmcnt(0)" ::: "memory");

    // ---- GEMM2: hout @ Wg1 (m=4), A-frags read from LDS ----
    floatx4 acc2[8];
#pragma unroll
    for (int c = 0; c < 8; ++c) acc2[c] = (floatx4){0.f, 0.f, 0.f, 0.f};
#pragma unroll
    for (int kc = 0; kc < 4; ++kc) {
        const float* ap = hbw + l15 * 132 + kc * 32 + quad * 8;
        float4 f0 = *(const float4*)(ap);
        float4 f1 = *(const float4*)(ap + 4);
        float fv[8] = {f0.x, f0.y, f0.z, f0.w, f1.x, f1.y, f1.z, f1.w};
        short8 ah, al;
#pragma unroll
        for (int j = 0; j < 8; ++j) {
            unsigned short hi = f2bf(fv[j]);
            ah[j] = (short)hi;
            al[j] = (short)f2bf(fv[j] - bf2f(hi));
        }
#pragma unroll
        for (int ct = 0; ct < 8; ++ct) {
            unsigned fb = ((((unsigned)(4 * 4 + kc) * 8 + ct) * 2) * 64 + lane) * 8;
            short8 bh = *(const short8*)(wsp + fb);
            short8 bl = *(const short8*)(wsp + fb + 512);
            acc2[ct] = __builtin_amdgcn_mfma_f32_16x16x32_bf16(ah, bh, acc2[ct], 0, 0, 0);
            acc2[ct] = __builtin_amdgcn_mfma_f32_16x16x32_bf16(ah, bl, acc2[ct], 0, 0, 0);
            acc2[ct] = __builtin_amdgcn_mfma_f32_16x16x32_bf16(al, bh, acc2[ct], 0, 0, 0);
        }
    }

    // epilogue 2: silu * Wg2, reduce cols -> gate -> xout
    float pr[4] = {0.f, 0.f, 0.f, 0.f};
#pragma unroll
    for (int ct = 0; ct < 8; ++ct) {
        int col = ct * 16 + l15;
        float b1 = bg1[col];
        float w2 = Wg2[col];
#pragma unroll
        for (int reg = 0; reg < 4; ++reg) {
            float z = acc2[ct][reg] + b1;
            pr[reg] += (z / (1.f + __expf(-z))) * w2;
        }
    }
#pragma unroll
    for (int off = 1; off < 16; off <<= 1) {
#pragma unroll
        for (int reg = 0; reg < 4; ++reg) pr[reg] += __shfl_xor(pr[reg], off);
    }
    if (l15 == 0) {
        float b2 = bg2[0];
#pragma unroll
        for (int reg = 0; reg < 4; ++reg) {
            int row = row0 + quad * 4 + reg;
            if (row < N_NODES) {
                float g = tanhf(pr[reg] + b2);
#pragma unroll
                for (int dd = 0; dd < 3; ++dd) {
                    int oo = row * 3 + dd;
                    xout[oo] = x[oo] + g * disp[oo];
                }
            }
        }
    }
}

extern "C" void kernel_launch(void* const* d_in, const int* in_sizes, int n_in,
                              void* d_out, int out_size, void* d_ws, size_t ws_size,
                              hipStream_t stream) {
    const float* h    = (const float*)d_in[0];
    const float* x    = (const float*)d_in[1];
    const int*   src  = (const int*)d_in[2];
    const int*   dst  = (const int*)d_in[3];
    const float* dist = (const float*)d_in[4];
    const float* Wq = (const float*)d_in[5];  const float* bq = (const float*)d_in[6];
    const float* Wk = (const float*)d_in[7];  const float* bk = (const float*)d_in[8];
    const float* Wv = (const float*)d_in[9];  const float* bv = (const float*)d_in[10];
    const float* Wo = (const float*)d_in[11]; const float* bo = (const float*)d_in[12];
    const float* Wd = (const float*)d_in[13]; const float* bd = (const float*)d_in[14];
    const float* Wg1 = (const float*)d_in[15]; const float* bg1 = (const float*)d_in[16];
    const float* Wg2 = (const float*)d_in[17]; const float* bg2 = (const float*)d_in[18];

    float* ws    = (float*)d_ws;
    float* q     = ws + OFF_Q;
    unsigned* kvp = (unsigned*)(ws + OFF_KV);
    float* disp  = ws + OFF_DISP;
    int* cnt     = (int*)(ws + OFF_CNT);
    int* rowptr  = (int*)(ws + OFF_ROWPTR);
    int2* esd    = (int2*)(ws + OFF_ESD);
    unsigned short* wsp = (unsigned short*)(ws + OFF_WSPLIT);
    // scan scratch in q region, consumed before k_qkv_scatter writes q
    int* loc    = (int*)(ws + OFF_Q);
    int* bsum   = (int*)(ws + OFF_Q + 500000u);
    // rank lives in the hupd_hi region: written by k_count, consumed by
    // k_qkv_scatter's scatter blocks, both before k_edge_node writes hupd_hi
    int* rank   = (int*)(ws + OFF_HHI);
    unsigned short* hupd_hi = (unsigned short*)(ws + OFF_HHI);
    unsigned short* hupd_lo = (unsigned short*)(ws + OFF_HLO);
    float* hout = (float*)d_out;
    float* xout = hout + (size_t)N_NODES * HIDDEN;

    const int nscan = (N_NODES + 1023) / 1024;    // 49

    k_prep<<<SPLITW_BLOCKS + ZERO_BLOCKS, 256, 0, stream>>>(Wq, Wk, Wv, Wo, Wg1, wsp, cnt);
    k_count<<<SCAT_BLOCKS, 256, 0, stream>>>(src, cnt, rank);
    k_scan1<<<nscan, 1024, 0, stream>>>(cnt, loc, bsum, N_NODES);
    k_scan23<<<ZERO_BLOCKS, 256, 0, stream>>>(loc, bsum, rowptr, N_NODES, nscan);
    k_qkv_scatter<<<QKV_TOTAL + SCAT_BLOCKS, 256, 0, stream>>>(
        h, wsp, bq, bk, bv, q, kvp, src, dst, dist, rowptr, rank, esd);
    k_edge_node<<<N_NODES / 4, 256, 0, stream>>>(q, kvp, x, esd, rowptr,
                                                 Wd, bd, hupd_hi, hupd_lo, disp);
    k_hout_gate<<<(N_NODES + 63) / 64, 256, 0, stream>>>(h, hupd_hi, hupd_lo, wsp,
                                                         bo, bg1, Wg2, bg2,
                                                         x, disp, hout, xout);
}